// Round 7
// baseline (225.564 us; speedup 1.0000x reference)
//
#include <hip/hip_runtime.h>
#include <hip/hip_bf16.h>

#define HEADS 16
#define DK 64
#define DM 1024
#define SEQ 2048
#define BATCH 2

using bf16x8 = __attribute__((ext_vector_type(8))) short;
using short4v = __attribute__((ext_vector_type(4))) short;
using f32x4 = __attribute__((ext_vector_type(4))) float;

// fp32 -> bf16 bits, round-to-nearest-even (inputs are finite)
static __device__ __forceinline__ short f2bf(float x) {
  union { float f; unsigned u; } c;
  c.f = x;
  unsigned r = (c.u + 0x7FFFu + ((c.u >> 16) & 1u)) >> 16;
  return (short)r;
}

// packed fp32x2 -> bf16x2 via the compiler's RNE packed convert
static __device__ __forceinline__ unsigned pk2bf(float lo, float hi) {
  union { __hip_bfloat162 h; unsigned u; } c;
  c.h = __float22bfloat162_rn(float2{lo, hi});
  return c.u;
}

// async global->LDS, 16B per lane; LDS dest is wave-uniform base + lane*16
static __device__ __forceinline__ void gload_lds16(const void* g, void* l) {
  __builtin_amdgcn_global_load_lds(
      (const __attribute__((address_space(1))) void*)g,
      (__attribute__((address_space(3))) void*)l, 16, 0, 0);
}

// ---------------------------------------------------------------------------
// Bulk fp32 -> bf16 conversion for q,k,v and the 4 weight matrices.
// ---------------------------------------------------------------------------
__global__ __launch_bounds__(256) void cvt7(
    const float* __restrict__ s0, const float* __restrict__ s1,
    const float* __restrict__ s2, const float* __restrict__ s3,
    const float* __restrict__ s4, const float* __restrict__ s5,
    const float* __restrict__ s6, short* d0, short* d1, short* d2, short* d3,
    short* d4, short* d5, short* d6) {
  const int y = blockIdx.y;
  const float* s;
  short* d;
  int n;
  switch (y) {
    case 0: s = s0; d = d0; n = BATCH * SEQ * DM; break;
    case 1: s = s1; d = d1; n = BATCH * SEQ * DM; break;
    case 2: s = s2; d = d2; n = BATCH * SEQ * DM; break;
    case 3: s = s3; d = d3; n = DM * DM; break;
    case 4: s = s4; d = d4; n = DM * DM; break;
    case 5: s = s5; d = d5; n = DM * DM; break;
    default: s = s6; d = d6; n = DM * DM; break;
  }
  const int n4 = n >> 2;
  const int stride = gridDim.x * 256;
  for (int i = blockIdx.x * 256 + threadIdx.x; i < n4; i += stride) {
    float4 v = ((const float4*)s)[i];
    short4v o;
    o.x = f2bf(v.x);
    o.y = f2bf(v.y);
    o.z = f2bf(v.z);
    o.w = f2bf(v.w);
    ((short4v*)d)[i] = o;
  }
}

// ---------------------------------------------------------------------------
// Merged QKV projection, BM=64 for occupancy: C = A @ W^T + bias.
// grid (DM/128, (B*S)/64, 3) = 1536 blocks -> 6 blocks/CU (24KB LDS).
// 4 waves: mh=(wave&1)*32 (2 frags), nh=(wave>>1)*64 (4 frags).
//   z=0,1: bf16 head layout [B,H,S,DK] ; z=2: transposed [B,H,DK,S] (V)
// z=0 (Q) pre-scaled by 0.125*log2(e) so attention softmax is exp2(|s|).
// ---------------------------------------------------------------------------
__global__ __launch_bounds__(256) void proj_qkv(
    const short* __restrict__ Aq, const short* __restrict__ Ak,
    const short* __restrict__ Av, const short* __restrict__ Wq_,
    const short* __restrict__ Wk_, const short* __restrict__ Wv_,
    const float* __restrict__ bq, const float* __restrict__ bk,
    const float* __restrict__ bv, short* __restrict__ Qh,
    short* __restrict__ Kh, short* __restrict__ Vt) {
  __shared__ short smem[12288];  // A 64x64 (4096) + W 128x64 (8192) = 24KB
  short* As = smem;
  short* Ws = smem + 4096;

  const int z = blockIdx.z;
  const short* A = z == 0 ? Aq : z == 1 ? Ak : Av;
  const short* W = z == 0 ? Wq_ : z == 1 ? Wk_ : Wv_;
  const float* bias = z == 0 ? bq : z == 1 ? bk : bv;
  short* C = z == 0 ? Qh : z == 1 ? Kh : Vt;
  const bool tr = (z == 2);

  const int tid = threadIdx.x;
  const int wave = tid >> 6, lane = tid & 63;
  const int quad = lane >> 4, l15 = lane & 15;
  const int n0 = blockIdx.x * 128, m0 = blockIdx.y * 64;
  const int mh = (wave & 1) * 32, nh = (wave >> 1) * 64;
  const int ldr = lane >> 3, ldc = lane & 7;

  f32x4 acc[2][4] = {};

  for (int k0 = 0; k0 < 1024; k0 += 64) {
    __syncthreads();
#pragma unroll
    for (int i = 0; i < 6; ++i) {  // 24 segs balanced: 6 per wave
      int seg = wave * 6 + i;
      if (seg < 8) {
        int r = seg * 8 + ldr;
        int kb = ldc ^ (r & 7);
        gload_lds16(&A[(size_t)(m0 + r) * 1024 + k0 + kb * 8], &As[seg * 512]);
      } else {
        int r = (seg - 8) * 8 + ldr;
        int kb = ldc ^ (r & 7);
        gload_lds16(&W[(size_t)(n0 + r) * 1024 + k0 + kb * 8],
                    &Ws[(seg - 8) * 512]);
      }
    }
    __syncthreads();
#pragma unroll
    for (int ks = 0; ks < 2; ++ks) {
      bf16x8 a[2], b[4];
      int kb = ks * 4 + quad;
#pragma unroll
      for (int f = 0; f < 2; ++f) {
        int rm = mh + f * 16 + l15;
        a[f] = *(const bf16x8*)&As[rm * 64 + (kb ^ (rm & 7)) * 8];
      }
#pragma unroll
      for (int f = 0; f < 4; ++f) {
        int rn = nh + f * 16 + l15;
        b[f] = *(const bf16x8*)&Ws[rn * 64 + (kb ^ (rn & 7)) * 8];
      }
#pragma unroll
      for (int mf = 0; mf < 2; ++mf)
#pragma unroll
        for (int nf = 0; nf < 4; ++nf)
          acc[mf][nf] = __builtin_amdgcn_mfma_f32_16x16x32_bf16(
              a[mf], b[nf], acc[mf][nf], 0, 0, 0);
    }
  }

  float bvv[4];
#pragma unroll
  for (int nf = 0; nf < 4; ++nf) bvv[nf] = bias[n0 + nh + nf * 16 + l15];

  __syncthreads();
  short* Cb = smem;

  if (!tr) {
    // 64 rows x 136 stride = 8704 shorts
    const float osc = (z == 0) ? 0.18033688011112042f : 1.0f;
#pragma unroll
    for (int mf = 0; mf < 2; ++mf)
#pragma unroll
      for (int nf = 0; nf < 4; ++nf)
#pragma unroll
        for (int r = 0; r < 4; ++r)
          Cb[(mh + mf * 16 + quad * 4 + r) * 136 + nh + nf * 16 + l15] =
              f2bf((acc[mf][nf][r] + bvv[nf]) * osc);
    __syncthreads();
#pragma unroll
    for (int j = 0; j < 4; ++j) {
      int cid = tid + 256 * j;  // 64 rows x 16 chunks
      int row = cid >> 4, cb = cid & 15;
      bf16x8 v = *(const bf16x8*)&Cb[row * 136 + cb * 8];
      int m = m0 + row, n = n0 + cb * 8;
      int b = m >> 11, s = m & (SEQ - 1), h = n >> 6, d = n & 63;
      *(bf16x8*)&C[((size_t)(b * HEADS + h) * SEQ + s) * DK + d] = v;
    }
  } else {
    // 128 n-rows x 72 stride = 9216 shorts
#pragma unroll
    for (int mf = 0; mf < 2; ++mf)
#pragma unroll
      for (int nf = 0; nf < 4; ++nf) {
        short4v p;
        p.x = f2bf(acc[mf][nf][0] + bvv[nf]);
        p.y = f2bf(acc[mf][nf][1] + bvv[nf]);
        p.z = f2bf(acc[mf][nf][2] + bvv[nf]);
        p.w = f2bf(acc[mf][nf][3] + bvv[nf]);
        *(short4v*)&Cb[(nh + nf * 16 + l15) * 72 + mh + mf * 16 + quad * 4] =
            p;
      }
    __syncthreads();
#pragma unroll
    for (int j = 0; j < 4; ++j) {
      int cid = tid + 256 * j;  // 128 n-rows x 8 m-chunks
      int row = cid >> 3, cb = cid & 7;
      bf16x8 v = *(const bf16x8*)&Cb[row * 72 + cb * 8];
      int n = n0 + row, m = m0 + cb * 8;
      int b = m >> 11, s = m & (SEQ - 1), h = n >> 6, d = n & 63;
      *(bf16x8*)&C[((size_t)(b * HEADS + h) * DK + d) * SEQ + s] = v;
    }
  }
}

// ---------------------------------------------------------------------------
// Output projection, BM=64: fp32 out = concat @ Wo^T + bo.
// grid (8, 64) = 512 blocks -> 2 blocks/CU (was 1 -> latency-starved).
// ---------------------------------------------------------------------------
__global__ __launch_bounds__(256) void proj_out(const short* __restrict__ A,
                                                const short* __restrict__ W,
                                                const float* __restrict__ bias,
                                                float* __restrict__ C) {
  __shared__ short smem[12288];
  short* As = smem;
  short* Ws = smem + 4096;

  const int tid = threadIdx.x;
  const int wave = tid >> 6, lane = tid & 63;
  const int quad = lane >> 4, l15 = lane & 15;
  const int n0 = blockIdx.x * 128, m0 = blockIdx.y * 64;
  const int mh = (wave & 1) * 32, nh = (wave >> 1) * 64;
  const int ldr = lane >> 3, ldc = lane & 7;

  f32x4 acc[2][4] = {};

  for (int k0 = 0; k0 < 1024; k0 += 64) {
    __syncthreads();
#pragma unroll
    for (int i = 0; i < 6; ++i) {
      int seg = wave * 6 + i;
      if (seg < 8) {
        int r = seg * 8 + ldr;
        int kb = ldc ^ (r & 7);
        gload_lds16(&A[(size_t)(m0 + r) * 1024 + k0 + kb * 8], &As[seg * 512]);
      } else {
        int r = (seg - 8) * 8 + ldr;
        int kb = ldc ^ (r & 7);
        gload_lds16(&W[(size_t)(n0 + r) * 1024 + k0 + kb * 8],
                    &Ws[(seg - 8) * 512]);
      }
    }
    __syncthreads();
#pragma unroll
    for (int ks = 0; ks < 2; ++ks) {
      bf16x8 a[2], b[4];
      int kb = ks * 4 + quad;
#pragma unroll
      for (int f = 0; f < 2; ++f) {
        int rm = mh + f * 16 + l15;
        a[f] = *(const bf16x8*)&As[rm * 64 + (kb ^ (rm & 7)) * 8];
      }
#pragma unroll
      for (int f = 0; f < 4; ++f) {
        int rn = nh + f * 16 + l15;
        b[f] = *(const bf16x8*)&Ws[rn * 64 + (kb ^ (rn & 7)) * 8];
      }
#pragma unroll
      for (int mf = 0; mf < 2; ++mf)
#pragma unroll
        for (int nf = 0; nf < 4; ++nf)
          acc[mf][nf] = __builtin_amdgcn_mfma_f32_16x16x32_bf16(
              a[mf], b[nf], acc[mf][nf], 0, 0, 0);
    }
  }

  float bvv[4];
#pragma unroll
  for (int nf = 0; nf < 4; ++nf) bvv[nf] = bias[n0 + nh + nf * 16 + l15];
#pragma unroll
  for (int mf = 0; mf < 2; ++mf)
#pragma unroll
    for (int nf = 0; nf < 4; ++nf)
#pragma unroll
      for (int r = 0; r < 4; ++r)
        C[(size_t)(m0 + mh + mf * 16 + quad * 4 + r) * 1024 + n0 + nh +
          nf * 16 + l15] = acc[mf][nf][r] + bvv[nf];
}

// ---------------------------------------------------------------------------
// Flash attention v8 = v7 (proven) + XCD-aware block swizzle:
//  - bijective remap o = 64*(lin&7) + lin>>3: XCD c gets logical blocks
//    [64c,64c+64) = heads [4c,4c+4) -> K/V working set 2MB, L2-resident.
//    Cuts cross-XCD K/V re-fetch (FETCH 70MB -> ~35MB) and makes staging
//    L2-hit latency class.
//  - rest identical to v7: 8 waves KV-split, sigma in-register P, packed
//    cvt, all-ones-MFMA row sums, exact partial combine.
// ---------------------------------------------------------------------------
__global__ __launch_bounds__(512, 4) void attn_mfma(
    const short* __restrict__ Qh, const short* __restrict__ Kh,
    const short* __restrict__ VtG, short* __restrict__ concat) {
  __shared__ __align__(16) short smem[4 * 64 * 64];  // 32KB
  __shared__ float Lsm[128];
  short* Kbuf = smem;              // [2][64*64]
  short* Vbuf = smem + 2 * 4096;   // [2][64*64]

  const int tid = threadIdx.x;
  const int wave = tid >> 6, lane = tid & 63;
  const int quad = lane >> 4, l15 = lane & 15;
  const int wq = wave & 3;   // q-row group
  const int wg = wave >> 2;  // key group
  // XCD swizzle: lin -> o so each XCD owns 4 consecutive heads
  const int lin = blockIdx.x + (blockIdx.y << 4);
  const int o = ((lin & 7) << 6) + (lin >> 3);
  const int bh = o >> 4;
  const int q0 = (o & 15) * 128;
  const size_t base = (size_t)bh * SEQ * DK;
  const int ldr = lane >> 3, ldc = lane & 7;
  const int NT = SEQ / 64;

  // resident Q B-fragments for this wave's 32 q-rows
  bf16x8 qf[2][2];
#pragma unroll
  for (int mf = 0; mf < 2; ++mf)
#pragma unroll
    for (int ks = 0; ks < 2; ++ks)
      qf[mf][ks] =
          *(const bf16x8*)&Qh[base +
                              (size_t)(q0 + wq * 32 + mf * 16 + l15) * 64 +
                              ks * 32 + quad * 8];

  bf16x8 ones;
#pragma unroll
  for (int i = 0; i < 8; ++i) ones[i] = (short)0x3F80;  // bf16 1.0

  f32x4 O[2][4] = {};    // partial over this wave's key half
  f32x4 Lacc[2] = {};    // partial row sums

  // sigma-permuted K-fragment rows for kf = 2wg + kfl
  int krow[2];
#pragma unroll
  for (int kfl = 0; kfl < 2; ++kfl)
    krow[kfl] = 32 * wg + 8 * (l15 >> 2) + 4 * kfl + (l15 & 3);

  auto stage = [&](int kt, int buf) {
    int r = wave * 8 + ldr;  // 8 waves x 8 rows = 64 rows
    int kswz = (r & 7) ^ (((r >> 3) & 3) << 1);
    gload_lds16(&Kh[base + (size_t)(kt * 64 + r) * 64 + (ldc ^ kswz) * 8],
                &Kbuf[buf * 4096 + wave * 512]);
    gload_lds16(&VtG[base + (size_t)r * SEQ + kt * 64 + (ldc ^ (r & 7)) * 8],
                &Vbuf[buf * 4096 + wave * 512]);
  };

  // prologue: tile 0 -> buf 0
  stage(0, 0);
  __syncthreads();

  int cur = 0;
  for (int kt = 0; kt < NT; ++kt) {
    if (kt + 1 < NT) stage(kt + 1, cur ^ 1);  // published by loop-end barrier

    const short* Ks = &Kbuf[cur * 4096];
    const short* Vs = &Vbuf[cur * 4096];

    // ---- S^T (this wave's 32 keys x 32 qrows) ----
    f32x4 sf[2][2] = {};
#pragma unroll
    for (int ks = 0; ks < 2; ++ks) {
      bf16x8 kfr[2];
      int kb = ks * 4 + quad;
#pragma unroll
      for (int kfl = 0; kfl < 2; ++kfl) {
        int n = krow[kfl];
        int kswz = (n & 7) ^ (((n >> 3) & 3) << 1);
        kfr[kfl] = *(const bf16x8*)&Ks[n * 64 + ((kb ^ kswz) << 3)];
      }
      __builtin_amdgcn_s_setprio(1);
#pragma unroll
      for (int kfl = 0; kfl < 2; ++kfl)
#pragma unroll
        for (int mf = 0; mf < 2; ++mf)
          sf[mf][kfl] = __builtin_amdgcn_mfma_f32_16x16x32_bf16(
              kfr[kfl], qf[mf][ks], sf[mf][kfl], 0, 0, 0);
      __builtin_amdgcn_s_setprio(0);
    }

    // ---- P = exp2(|S|) -> packed bf16 PV A-fragment (keys 32wg+8quad+j) ----
    bf16x8 pa[2];
#pragma unroll
    for (int mf = 0; mf < 2; ++mf) {
      float e[8];
#pragma unroll
      for (int kfl = 0; kfl < 2; ++kfl)
#pragma unroll
        for (int r = 0; r < 4; ++r)
          e[kfl * 4 + r] = __builtin_amdgcn_exp2f(fabsf(sf[mf][kfl][r]));
      union { unsigned u[4]; bf16x8 v; } t;
      t.u[0] = pk2bf(e[0], e[1]);
      t.u[1] = pk2bf(e[2], e[3]);
      t.u[2] = pk2bf(e[4], e[5]);
      t.u[3] = pk2bf(e[6], e[7]);
      pa[mf] = t.v;
    }

    // ---- O += P.V ; L += P.1 over this wave's key half ----
    {
      int gb = wg * 4 + quad;
      bf16x8 bvf[4];
#pragma unroll
      for (int nf = 0; nf < 4; ++nf) {
        int d = nf * 16 + l15;
        bvf[nf] = *(const bf16x8*)&Vs[d * 64 + ((gb ^ (d & 7)) << 3)];
      }
      __builtin_amdgcn_s_setprio(1);
#pragma unroll
      for (int mf = 0; mf < 2; ++mf) {
#pragma unroll
        for (int nf = 0; nf < 4; ++nf)
          O[mf][nf] = __builtin_amdgcn_mfma_f32_16x16x32_bf16(
              pa[mf], bvf[nf], O[mf][nf], 0, 0, 0);
        Lacc[mf] = __builtin_amdgcn_mfma_f32_16x16x32_bf16(pa[mf], ones,
                                                           Lacc[mf], 0, 0, 0);
      }
      __builtin_amdgcn_s_setprio(0);
    }

    __syncthreads();  // drains prefetch DMA + all reads of buf cur
    cur ^= 1;
  }

  // ---- combine key-group partials (exact: no max-rescale in this softmax) --
  float* Osm = (float*)smem;  // 32KB, overlays K/V buffers (all reads done)
  if (wg == 1) {
#pragma unroll
    for (int mf = 0; mf < 2; ++mf)
#pragma unroll
      for (int nf = 0; nf < 4; ++nf) {
        int d = nf * 16 + l15;
        int rowb = (wq * 32 + mf * 16 + quad * 4) ^ ((d & 7) << 2);
        *(f32x4*)&Osm[d * 128 + rowb] = O[mf][nf];
      }
    if (l15 == 0)
#pragma unroll
      for (int mf = 0; mf < 2; ++mf)
#pragma unroll
        for (int r = 0; r < 4; ++r)
          Lsm[wq * 32 + mf * 16 + quad * 4 + r] = Lacc[mf][r];
  }
  __syncthreads();

  float inv_[2][4];
  if (wg == 0) {
#pragma unroll
    for (int mf = 0; mf < 2; ++mf)
#pragma unroll
      for (int nf = 0; nf < 4; ++nf) {
        int d = nf * 16 + l15;
        int rowb = (wq * 32 + mf * 16 + quad * 4) ^ ((d & 7) << 2);
        O[mf][nf] += *(const f32x4*)&Osm[d * 128 + rowb];
      }
#pragma unroll
    for (int mf = 0; mf < 2; ++mf)
#pragma unroll
      for (int r = 0; r < 4; ++r)
        inv_[mf][r] =
            1.f / (Lacc[mf][r] + Lsm[wq * 32 + mf * 16 + quad * 4 + r]);
  }
  __syncthreads();  // all Osm reads done before bf16 staging overwrites

  short* Es = smem;  // 128x64 bf16, granule-swizzled
  if (wg == 0) {
#pragma unroll
    for (int mf = 0; mf < 2; ++mf)
#pragma unroll
      for (int nf = 0; nf < 4; ++nf)
#pragma unroll
        for (int r = 0; r < 4; ++r) {
          int rw = wq * 32 + mf * 16 + quad * 4 + r;
          int d = nf * 16 + l15;
          Es[rw * 64 + (((d >> 3) ^ (rw & 7)) << 3) + (d & 7)] =
              f2bf(O[mf][nf][r] * inv_[mf][r]);
        }
  }
  __syncthreads();
  const int b = bh >> 4, h = bh & 15;
#pragma unroll
  for (int j = 0; j < 2; ++j) {
    int cid = tid + 512 * j;  // 128 rows x 8 granules
    int rw = cid >> 3, g = cid & 7;
    bf16x8 v = *(const bf16x8*)&Es[rw * 64 + ((g ^ (rw & 7)) << 3)];
    *(bf16x8*)&concat[((size_t)(b * SEQ + q0 + rw)) * DM + h * 64 + g * 8] = v;
  }
}

extern "C" void kernel_launch(void* const* d_in, const int* in_sizes, int n_in,
                              void* d_out, int out_size, void* d_ws,
                              size_t ws_size, hipStream_t stream) {
  const float* q = (const float*)d_in[0];
  const float* k = (const float*)d_in[1];
  const float* v = (const float*)d_in[2];
  const float* Wq = (const float*)d_in[3];
  const float* bq = (const float*)d_in[4];
  const float* Wk = (const float*)d_in[5];
  const float* bk = (const float*)d_in[6];
  const float* Wv = (const float*)d_in[7];
  const float* bv = (const float*)d_in[8];
  const float* Wo = (const float*)d_in[9];
  const float* bo = (const float*)d_in[10];

  short* ws = (short*)d_ws;
  const size_t T4 = (size_t)BATCH * SEQ * DM;  // 4M elements
  const size_t T1 = (size_t)DM * DM;           // 1M elements
  short* qb = ws;
  short* kb_ = ws + T4;
  short* vb = ws + 2 * T4;
  short* Wqb = ws + 3 * T4;
  short* Wkb = Wqb + T1;
  short* Wvb = Wqb + 2 * T1;
  short* Wob = Wqb + 3 * T1;
  short* Qh = Wqb + 4 * T1;
  short* Kh = Qh + T4;
  short* VtG = Qh + 2 * T4;
  short* cc = Qh + 3 * T4;

  cvt7<<<dim3(1024, 7), 256, 0, stream>>>(q, k, v, Wq, Wk, Wv, Wo, qb, kb_, vb,
                                          Wqb, Wkb, Wvb, Wob);

  proj_qkv<<<dim3(DM / 128, (BATCH * SEQ) / 64, 3), 256, 0, stream>>>(
      qb, kb_, vb, Wqb, Wkb, Wvb, bq, bk, bv, Qh, Kh, VtG);

  attn_mfma<<<dim3(SEQ / 128, BATCH * HEADS), 512, 0, stream>>>(Qh, Kh, VtG,
                                                                cc);

  proj_out<<<dim3(DM / 128, (BATCH * SEQ) / 64), 256, 0, stream>>>(
      cc, Wob, bo, (float*)d_out);
}

// Round 8
// 219.576 us; speedup vs baseline: 1.0273x; 1.0273x over previous
//
#include <hip/hip_runtime.h>
#include <hip/hip_bf16.h>

#define HEADS 16
#define DK 64
#define DM 1024
#define SEQ 2048
#define BATCH 2

using bf16x8 = __attribute__((ext_vector_type(8))) short;
using short4v = __attribute__((ext_vector_type(4))) short;
using f32x4 = __attribute__((ext_vector_type(4))) float;

// fp32 -> bf16 bits, round-to-nearest-even (inputs are finite)
static __device__ __forceinline__ short f2bf(float x) {
  union { float f; unsigned u; } c;
  c.f = x;
  unsigned r = (c.u + 0x7FFFu + ((c.u >> 16) & 1u)) >> 16;
  return (short)r;
}

// packed fp32x2 -> bf16x2 via the compiler's RNE packed convert
static __device__ __forceinline__ unsigned pk2bf(float lo, float hi) {
  union { __hip_bfloat162 h; unsigned u; } c;
  c.h = __float22bfloat162_rn(float2{lo, hi});
  return c.u;
}

// async global->LDS, 16B per lane; LDS dest is wave-uniform base + lane*16
static __device__ __forceinline__ void gload_lds16(const void* g, void* l) {
  __builtin_amdgcn_global_load_lds(
      (const __attribute__((address_space(1))) void*)g,
      (__attribute__((address_space(3))) void*)l, 16, 0, 0);
}

// ---------------------------------------------------------------------------
// Bulk fp32 -> bf16 conversion for q,k,v and the 4 weight matrices.
// ---------------------------------------------------------------------------
__global__ __launch_bounds__(256) void cvt7(
    const float* __restrict__ s0, const float* __restrict__ s1,
    const float* __restrict__ s2, const float* __restrict__ s3,
    const float* __restrict__ s4, const float* __restrict__ s5,
    const float* __restrict__ s6, short* d0, short* d1, short* d2, short* d3,
    short* d4, short* d5, short* d6) {
  const int y = blockIdx.y;
  const float* s;
  short* d;
  int n;
  switch (y) {
    case 0: s = s0; d = d0; n = BATCH * SEQ * DM; break;
    case 1: s = s1; d = d1; n = BATCH * SEQ * DM; break;
    case 2: s = s2; d = d2; n = BATCH * SEQ * DM; break;
    case 3: s = s3; d = d3; n = DM * DM; break;
    case 4: s = s4; d = d4; n = DM * DM; break;
    case 5: s = s5; d = d5; n = DM * DM; break;
    default: s = s6; d = d6; n = DM * DM; break;
  }
  const int n4 = n >> 2;
  const int stride = gridDim.x * 256;
  for (int i = blockIdx.x * 256 + threadIdx.x; i < n4; i += stride) {
    float4 v = ((const float4*)s)[i];
    short4v o;
    o.x = f2bf(v.x);
    o.y = f2bf(v.y);
    o.z = f2bf(v.z);
    o.w = f2bf(v.w);
    ((short4v*)d)[i] = o;
  }
}

// ---------------------------------------------------------------------------
// Merged QKV projection, BM=64: C = A @ W^T + bias (unchanged from round 7).
// ---------------------------------------------------------------------------
__global__ __launch_bounds__(256) void proj_qkv(
    const short* __restrict__ Aq, const short* __restrict__ Ak,
    const short* __restrict__ Av, const short* __restrict__ Wq_,
    const short* __restrict__ Wk_, const short* __restrict__ Wv_,
    const float* __restrict__ bq, const float* __restrict__ bk,
    const float* __restrict__ bv, short* __restrict__ Qh,
    short* __restrict__ Kh, short* __restrict__ Vt) {
  __shared__ short smem[12288];  // A 64x64 (4096) + W 128x64 (8192) = 24KB
  short* As = smem;
  short* Ws = smem + 4096;

  const int z = blockIdx.z;
  const short* A = z == 0 ? Aq : z == 1 ? Ak : Av;
  const short* W = z == 0 ? Wq_ : z == 1 ? Wk_ : Wv_;
  const float* bias = z == 0 ? bq : z == 1 ? bk : bv;
  short* C = z == 0 ? Qh : z == 1 ? Kh : Vt;
  const bool tr = (z == 2);

  const int tid = threadIdx.x;
  const int wave = tid >> 6, lane = tid & 63;
  const int quad = lane >> 4, l15 = lane & 15;
  const int n0 = blockIdx.x * 128, m0 = blockIdx.y * 64;
  const int mh = (wave & 1) * 32, nh = (wave >> 1) * 64;
  const int ldr = lane >> 3, ldc = lane & 7;

  f32x4 acc[2][4] = {};

  for (int k0 = 0; k0 < 1024; k0 += 64) {
    __syncthreads();
#pragma unroll
    for (int i = 0; i < 6; ++i) {  // 24 segs balanced: 6 per wave
      int seg = wave * 6 + i;
      if (seg < 8) {
        int r = seg * 8 + ldr;
        int kb = ldc ^ (r & 7);
        gload_lds16(&A[(size_t)(m0 + r) * 1024 + k0 + kb * 8], &As[seg * 512]);
      } else {
        int r = (seg - 8) * 8 + ldr;
        int kb = ldc ^ (r & 7);
        gload_lds16(&W[(size_t)(n0 + r) * 1024 + k0 + kb * 8],
                    &Ws[(seg - 8) * 512]);
      }
    }
    __syncthreads();
#pragma unroll
    for (int ks = 0; ks < 2; ++ks) {
      bf16x8 a[2], b[4];
      int kb = ks * 4 + quad;
#pragma unroll
      for (int f = 0; f < 2; ++f) {
        int rm = mh + f * 16 + l15;
        a[f] = *(const bf16x8*)&As[rm * 64 + (kb ^ (rm & 7)) * 8];
      }
#pragma unroll
      for (int f = 0; f < 4; ++f) {
        int rn = nh + f * 16 + l15;
        b[f] = *(const bf16x8*)&Ws[rn * 64 + (kb ^ (rn & 7)) * 8];
      }
#pragma unroll
      for (int mf = 0; mf < 2; ++mf)
#pragma unroll
        for (int nf = 0; nf < 4; ++nf)
          acc[mf][nf] = __builtin_amdgcn_mfma_f32_16x16x32_bf16(
              a[mf], b[nf], acc[mf][nf], 0, 0, 0);
    }
  }

  float bvv[4];
#pragma unroll
  for (int nf = 0; nf < 4; ++nf) bvv[nf] = bias[n0 + nh + nf * 16 + l15];

  __syncthreads();
  short* Cb = smem;

  if (!tr) {
    const float osc = (z == 0) ? 0.18033688011112042f : 1.0f;
#pragma unroll
    for (int mf = 0; mf < 2; ++mf)
#pragma unroll
      for (int nf = 0; nf < 4; ++nf)
#pragma unroll
        for (int r = 0; r < 4; ++r)
          Cb[(mh + mf * 16 + quad * 4 + r) * 136 + nh + nf * 16 + l15] =
              f2bf((acc[mf][nf][r] + bvv[nf]) * osc);
    __syncthreads();
#pragma unroll
    for (int j = 0; j < 4; ++j) {
      int cid = tid + 256 * j;  // 64 rows x 16 chunks
      int row = cid >> 4, cb = cid & 15;
      bf16x8 v = *(const bf16x8*)&Cb[row * 136 + cb * 8];
      int m = m0 + row, n = n0 + cb * 8;
      int b = m >> 11, s = m & (SEQ - 1), h = n >> 6, d = n & 63;
      *(bf16x8*)&C[((size_t)(b * HEADS + h) * SEQ + s) * DK + d] = v;
    }
  } else {
#pragma unroll
    for (int mf = 0; mf < 2; ++mf)
#pragma unroll
      for (int nf = 0; nf < 4; ++nf) {
        short4v p;
        p.x = f2bf(acc[mf][nf][0] + bvv[nf]);
        p.y = f2bf(acc[mf][nf][1] + bvv[nf]);
        p.z = f2bf(acc[mf][nf][2] + bvv[nf]);
        p.w = f2bf(acc[mf][nf][3] + bvv[nf]);
        *(short4v*)&Cb[(nh + nf * 16 + l15) * 72 + mh + mf * 16 + quad * 4] =
            p;
      }
    __syncthreads();
#pragma unroll
    for (int j = 0; j < 4; ++j) {
      int cid = tid + 256 * j;  // 128 n-rows x 8 m-chunks
      int row = cid >> 3, cb = cid & 7;
      bf16x8 v = *(const bf16x8*)&Cb[row * 72 + cb * 8];
      int n = n0 + row, m = m0 + cb * 8;
      int b = m >> 11, s = m & (SEQ - 1), h = n >> 6, d = n & 63;
      *(bf16x8*)&C[((size_t)(b * HEADS + h) * DK + d) * SEQ + s] = v;
    }
  }
}

// ---------------------------------------------------------------------------
// Output projection, BM=64 (unchanged from round 7).
// ---------------------------------------------------------------------------
__global__ __launch_bounds__(256) void proj_out(const short* __restrict__ A,
                                                const short* __restrict__ W,
                                                const float* __restrict__ bias,
                                                float* __restrict__ C) {
  __shared__ short smem[12288];
  short* As = smem;
  short* Ws = smem + 4096;

  const int tid = threadIdx.x;
  const int wave = tid >> 6, lane = tid & 63;
  const int quad = lane >> 4, l15 = lane & 15;
  const int n0 = blockIdx.x * 128, m0 = blockIdx.y * 64;
  const int mh = (wave & 1) * 32, nh = (wave >> 1) * 64;
  const int ldr = lane >> 3, ldc = lane & 7;

  f32x4 acc[2][4] = {};

  for (int k0 = 0; k0 < 1024; k0 += 64) {
    __syncthreads();
#pragma unroll
    for (int i = 0; i < 6; ++i) {
      int seg = wave * 6 + i;
      if (seg < 8) {
        int r = seg * 8 + ldr;
        int kb = ldc ^ (r & 7);
        gload_lds16(&A[(size_t)(m0 + r) * 1024 + k0 + kb * 8], &As[seg * 512]);
      } else {
        int r = (seg - 8) * 8 + ldr;
        int kb = ldc ^ (r & 7);
        gload_lds16(&W[(size_t)(n0 + r) * 1024 + k0 + kb * 8],
                    &Ws[(seg - 8) * 512]);
      }
    }
    __syncthreads();
#pragma unroll
    for (int ks = 0; ks < 2; ++ks) {
      bf16x8 a[2], b[4];
      int kb = ks * 4 + quad;
#pragma unroll
      for (int f = 0; f < 2; ++f) {
        int rm = mh + f * 16 + l15;
        a[f] = *(const bf16x8*)&As[rm * 64 + (kb ^ (rm & 7)) * 8];
      }
#pragma unroll
      for (int f = 0; f < 4; ++f) {
        int rn = nh + f * 16 + l15;
        b[f] = *(const bf16x8*)&Ws[rn * 64 + (kb ^ (rn & 7)) * 8];
      }
#pragma unroll
      for (int mf = 0; mf < 2; ++mf)
#pragma unroll
        for (int nf = 0; nf < 4; ++nf)
          acc[mf][nf] = __builtin_amdgcn_mfma_f32_16x16x32_bf16(
              a[mf], b[nf], acc[mf][nf], 0, 0, 0);
    }
  }

  float bvv[4];
#pragma unroll
  for (int nf = 0; nf < 4; ++nf) bvv[nf] = bias[n0 + nh + nf * 16 + l15];
#pragma unroll
  for (int mf = 0; mf < 2; ++mf)
#pragma unroll
    for (int nf = 0; nf < 4; ++nf)
#pragma unroll
      for (int r = 0; r < 4; ++r)
        C[(size_t)(m0 + mh + mf * 16 + quad * 4 + r) * 1024 + n0 + nh +
          nf * 16 + l15] = acc[mf][nf][r] + bvv[nf];
}

// ---------------------------------------------------------------------------
// Flash attention v9 = v7 structure with KVBLK=128 (halved barrier chains):
//  - 8 waves (wq, wg): wq owns q-rows wq*32..+31; wg owns keys
//    [64wg, 64wg+64) of each 128-key tile. Per-wave tile body = v6's
//    hardware-verified 64-key sigma map, offset by 64wg:
//      krow[kfl] = 64wg + 32(kfl>>1) + 8(l15>>2) + 4(kfl&1) + (l15&3)
//      pa[mf][l] slot j -> key 64wg + 32l + 8quad + j
//      V chunk gb = 8wg + 4l + quad (16 chunks/row, XOR swz c^((d&7)<<1))
//  - NT = 16 tiles (was 32): per-tile barrier-chain stall amortized 2x.
//  - exact partial combine across wg (no running max in this softmax).
//  - packed v_cvt_pk P; all-ones-MFMA row sums; s_setprio; XCD swizzle.
// LDS: K 2x16KB + V 2x16KB = 64KB (grid already caps at 2 blocks/CU).
// ---------------------------------------------------------------------------
__global__ __launch_bounds__(512, 4) void attn_mfma(
    const short* __restrict__ Qh, const short* __restrict__ Kh,
    const short* __restrict__ VtG, short* __restrict__ concat) {
  __shared__ __align__(16) short smem[32768];  // 64KB
  __shared__ float Lsm[128];
  short* Kbuf = smem;               // [2][128*64]
  short* Vbuf = smem + 2 * 8192;    // [2][64*128]

  const int tid = threadIdx.x;
  const int wave = tid >> 6, lane = tid & 63;
  const int quad = lane >> 4, l15 = lane & 15;
  const int wq = wave & 3;   // q-row group
  const int wg = wave >> 2;  // key group (64 keys each)
  // XCD swizzle: each XCD owns 4 consecutive heads (K/V L2-resident)
  const int lin = blockIdx.x + (blockIdx.y << 4);
  const int o = ((lin & 7) << 6) + (lin >> 3);
  const int bh = o >> 4;
  const int q0 = (o & 15) * 128;
  const size_t base = (size_t)bh * SEQ * DK;
  const int ldr = lane >> 3, ldc = lane & 7;
  const int NT = SEQ / 128;

  // resident Q B-fragments for this wave's 32 q-rows
  bf16x8 qf[2][2];
#pragma unroll
  for (int mf = 0; mf < 2; ++mf)
#pragma unroll
    for (int ks = 0; ks < 2; ++ks)
      qf[mf][ks] =
          *(const bf16x8*)&Qh[base +
                              (size_t)(q0 + wq * 32 + mf * 16 + l15) * 64 +
                              ks * 32 + quad * 8];

  bf16x8 ones;
#pragma unroll
  for (int i = 0; i < 8; ++i) ones[i] = (short)0x3F80;  // bf16 1.0

  f32x4 O[2][4] = {};  // partial over this wave's 64-key groups
  f32x4 Lacc[2] = {};

  // sigma-permuted K rows, kfl = 0..3 (v6 map + 64wg offset)
  int krow[4];
#pragma unroll
  for (int kfl = 0; kfl < 4; ++kfl)
    krow[kfl] =
        64 * wg + 32 * (kfl >> 1) + 8 * (l15 >> 2) + 4 * (kfl & 1) + (l15 & 3);

  auto stage = [&](int kt, int buf) {
#pragma unroll
    for (int i = 0; i < 2; ++i) {
      int seg = wave * 2 + i;
      {  // K: seg covers key-rows 8s..8s+7 (of 128), 64 shorts each
        int r = seg * 8 + ldr;
        int kswz = (r & 7) ^ (((r >> 3) & 3) << 1);
        gload_lds16(
            &Kh[base + (size_t)(kt * 128 + r) * 64 + (ldc ^ kswz) * 8],
            &Kbuf[buf * 8192 + seg * 512]);
      }
      {  // V: seg covers d-rows 4s..4s+3, 128 shorts each (16 chunks)
        int r = seg * 4 + (lane >> 4);
        int c = lane & 15;
        gload_lds16(&VtG[base + (size_t)r * SEQ + kt * 128 +
                         (c ^ ((r & 7) << 1)) * 8],
                    &Vbuf[buf * 8192 + seg * 512]);
      }
    }
  };

  // prologue: tile 0 -> buf 0
  stage(0, 0);
  __syncthreads();

  int cur = 0;
  for (int kt = 0; kt < NT; ++kt) {
    if (kt + 1 < NT) stage(kt + 1, cur ^ 1);  // published by loop-end barrier

    const short* Ks = &Kbuf[cur * 8192];
    const short* Vs = &Vbuf[cur * 8192];

    // ---- S^T over this wave's 64 keys (v6 body, wg-offset) ----
    f32x4 sf[2][4] = {};
#pragma unroll
    for (int ks = 0; ks < 2; ++ks) {
      bf16x8 kfr[4];
      int kb = ks * 4 + quad;
#pragma unroll
      for (int kfl = 0; kfl < 4; ++kfl) {
        int n = krow[kfl];
        int kswz = (n & 7) ^ (((n >> 3) & 3) << 1);
        kfr[kfl] = *(const bf16x8*)&Ks[n * 64 + ((kb ^ kswz) << 3)];
      }
      __builtin_amdgcn_s_setprio(1);
#pragma unroll
      for (int kfl = 0; kfl < 4; ++kfl)
#pragma unroll
        for (int mf = 0; mf < 2; ++mf)
          sf[mf][kfl] = __builtin_amdgcn_mfma_f32_16x16x32_bf16(
              kfr[kfl], qf[mf][ks], sf[mf][kfl], 0, 0, 0);
      __builtin_amdgcn_s_setprio(0);
    }

    // ---- P = exp2(|S|) -> packed bf16 PV A-frags (keys 64wg+32l+8quad+j) --
    bf16x8 pa[2][2];
#pragma unroll
    for (int mf = 0; mf < 2; ++mf)
#pragma unroll
      for (int l = 0; l < 2; ++l) {
        float e[8];
#pragma unroll
        for (int half = 0; half < 2; ++half)
#pragma unroll
          for (int r = 0; r < 4; ++r)
            e[half * 4 + r] =
                __builtin_amdgcn_exp2f(fabsf(sf[mf][2 * l + half][r]));
        union { unsigned u[4]; bf16x8 v; } t;
        t.u[0] = pk2bf(e[0], e[1]);
        t.u[1] = pk2bf(e[2], e[3]);
        t.u[2] = pk2bf(e[4], e[5]);
        t.u[3] = pk2bf(e[6], e[7]);
        pa[mf][l] = t.v;
      }

    // ---- O += P.V ; L += P.1 over this wave's 64 keys ----
#pragma unroll
    for (int l = 0; l < 2; ++l) {
      int gb = 8 * wg + 4 * l + quad;
      bf16x8 bvf[4];
#pragma unroll
      for (int nf = 0; nf < 4; ++nf) {
        int d = nf * 16 + l15;
        bvf[nf] = *(const bf16x8*)&Vs[d * 128 + ((gb ^ ((d & 7) << 1)) << 3)];
      }
      __builtin_amdgcn_s_setprio(1);
#pragma unroll
      for (int mf = 0; mf < 2; ++mf) {
#pragma unroll
        for (int nf = 0; nf < 4; ++nf)
          O[mf][nf] = __builtin_amdgcn_mfma_f32_16x16x32_bf16(
              pa[mf][l], bvf[nf], O[mf][nf], 0, 0, 0);
        Lacc[mf] = __builtin_amdgcn_mfma_f32_16x16x32_bf16(pa[mf][l], ones,
                                                           Lacc[mf], 0, 0, 0);
      }
      __builtin_amdgcn_s_setprio(0);
    }

    __syncthreads();  // drains prefetch DMA + all reads of buf cur
    cur ^= 1;
  }

  // ---- combine key-group partials (exact: no max-rescale) ----
  float* Osm = (float*)smem;  // 32KB of the 64KB region (all reads done)
  if (wg == 1) {
#pragma unroll
    for (int mf = 0; mf < 2; ++mf)
#pragma unroll
      for (int nf = 0; nf < 4; ++nf) {
        int d = nf * 16 + l15;
        int rowb = (wq * 32 + mf * 16 + quad * 4) ^ ((d & 7) << 2);
        *(f32x4*)&Osm[d * 128 + rowb] = O[mf][nf];
      }
    if (l15 == 0)
#pragma unroll
      for (int mf = 0; mf < 2; ++mf)
#pragma unroll
        for (int r = 0; r < 4; ++r)
          Lsm[wq * 32 + mf * 16 + quad * 4 + r] = Lacc[mf][r];
  }
  __syncthreads();

  float inv_[2][4];
  if (wg == 0) {
#pragma unroll
    for (int mf = 0; mf < 2; ++mf)
#pragma unroll
      for (int nf = 0; nf < 4; ++nf) {
        int d = nf * 16 + l15;
        int rowb = (wq * 32 + mf * 16 + quad * 4) ^ ((d & 7) << 2);
        O[mf][nf] += *(const f32x4*)&Osm[d * 128 + rowb];
      }
#pragma unroll
    for (int mf = 0; mf < 2; ++mf)
#pragma unroll
      for (int r = 0; r < 4; ++r)
        inv_[mf][r] =
            1.f / (Lacc[mf][r] + Lsm[wq * 32 + mf * 16 + quad * 4 + r]);
  }
  __syncthreads();  // all Osm reads done before bf16 staging overwrites

  short* Es = smem;  // 128x64 bf16, granule-swizzled
  if (wg == 0) {
#pragma unroll
    for (int mf = 0; mf < 2; ++mf)
#pragma unroll
      for (int nf = 0; nf < 4; ++nf)
#pragma unroll
        for (int r = 0; r < 4; ++r) {
          int rw = wq * 32 + mf * 16 + quad * 4 + r;
          int d = nf * 16 + l15;
          Es[rw * 64 + (((d >> 3) ^ (rw & 7)) << 3) + (d & 7)] =
              f2bf(O[mf][nf][r] * inv_[mf][r]);
        }
  }
  __syncthreads();
  const int b = bh >> 4, h = bh & 15;
#pragma unroll
  for (int j = 0; j < 2; ++j) {
    int cid = tid + 512 * j;  // 128 rows x 8 granules
    int rw = cid >> 3, g = cid & 7;
    bf16x8 v = *(const bf16x8*)&Es[rw * 64 + ((g ^ (rw & 7)) << 3)];
    *(bf16x8*)&concat[((size_t)(b * SEQ + q0 + rw)) * DM + h * 64 + g * 8] = v;
  }
}

extern "C" void kernel_launch(void* const* d_in, const int* in_sizes, int n_in,
                              void* d_out, int out_size, void* d_ws,
                              size_t ws_size, hipStream_t stream) {
  const float* q = (const float*)d_in[0];
  const float* k = (const float*)d_in[1];
  const float* v = (const float*)d_in[2];
  const float* Wq = (const float*)d_in[3];
  const float* bq = (const float*)d_in[4];
  const float* Wk = (const float*)d_in[5];
  const float* bk = (const float*)d_in[6];
  const float* Wv = (const float*)d_in[7];
  const float* bv = (const float*)d_in[8];
  const float* Wo = (const float*)d_in[9];
  const float* bo = (const float*)d_in[10];

  short* ws = (short*)d_ws;
  const size_t T4 = (size_t)BATCH * SEQ * DM;  // 4M elements
  const size_t T1 = (size_t)DM * DM;           // 1M elements
  short* qb = ws;
  short* kb_ = ws + T4;
  short* vb = ws + 2 * T4;
  short* Wqb = ws + 3 * T4;
  short* Wkb = Wqb + T1;
  short* Wvb = Wqb + 2 * T1;
  short* Wob = Wqb + 3 * T1;
  short* Qh = Wqb + 4 * T1;
  short* Kh = Qh + T4;
  short* VtG = Qh + 2 * T4;
  short* cc = Qh + 3 * T4;

  cvt7<<<dim3(1024, 7), 256, 0, stream>>>(q, k, v, Wq, Wk, Wv, Wo, qb, kb_, vb,
                                          Wqb, Wkb, Wvb, Wob);

  proj_qkv<<<dim3(DM / 128, (BATCH * SEQ) / 64, 3), 256, 0, stream>>>(
      qb, kb_, vb, Wqb, Wkb, Wvb, bq, bk, bv, Qh, Kh, VtG);

  attn_mfma<<<dim3(SEQ / 128, BATCH * HEADS), 512, 0, stream>>>(Qh, Kh, VtG,
                                                                cc);

  proj_out<<<dim3(DM / 128, (BATCH * SEQ) / 64), 256, 0, stream>>>(
      cc, Wob, bo, (float*)d_out);
}